// Round 8
// baseline (315.234 us; speedup 1.0000x reference)
//
#include <hip/hip_runtime.h>

#define FEATS 64
#define TILE 16          // dst nodes per bucket
#define MAX_NB 6400      // supports N <= 102400 at TILE=16
#define CH 8192          // edges per build chunk (196 chunks)
#define SORT_CAP 2048    // max bucket size the sorter handles (avg is 256)

__device__ __forceinline__ float bf2f(unsigned short b) {
    unsigned u = (unsigned)b << 16;
    float f; __builtin_memcpy(&f, &u, 4); return f;
}
__device__ __forceinline__ unsigned short f2bf(float f) {   // round-to-nearest-even
    unsigned u; __builtin_memcpy(&u, &f, 4);
    u += 0x7FFFu + ((u >> 16) & 1u);
    return (unsigned short)(u >> 16);
}

// ---- scale: hs = bf16(feat * norm); 4 elems/thread ----
__global__ __launch_bounds__(256) void scale_kernel(
    const float* __restrict__ feat, const float* __restrict__ norm,
    unsigned short* __restrict__ out, int n4) {
    const int i = blockIdx.x * 256 + threadIdx.x;
    if (i >= n4) return;
    float4 v = reinterpret_cast<const float4*>(feat)[i];
    const float nv = norm[i >> 4];                  // 16 float4 per 64-feat row
    uint2 p;
    p.x = (unsigned)f2bf(v.x * nv) | ((unsigned)f2bf(v.y * nv) << 16);
    p.y = (unsigned)f2bf(v.z * nv) | ((unsigned)f2bf(v.w * nv) << 16);
    reinterpret_cast<uint2*>(out)[i] = p;
}

// ---- build pass 1: per-chunk histogram over dst buckets ----
__global__ __launch_bounds__(1024) void hist_pass(
    const int* __restrict__ dst, int* __restrict__ hist, int E, int NB) {
    __shared__ int lh[MAX_NB];
    for (int i = threadIdx.x; i < NB; i += 1024) lh[i] = 0;
    __syncthreads();
    const int k  = blockIdx.x;
    const int e0 = k * CH, e1 = min(E, e0 + CH);
    for (int e = e0 + threadIdx.x; e < e1; e += 1024)
        atomicAdd(&lh[dst[e] >> 4], 1);
    __syncthreads();
    for (int b = threadIdx.x; b < NB; b += 1024)
        hist[(size_t)k * NB + b] = lh[b];
}

// ---- build pass 2: per-bucket exclusive scan across chunks (in place), totals ----
__global__ __launch_bounds__(256) void bucket_scan(
    int* hist, int* __restrict__ btotal, int NB, int NCHUNK) {
    __shared__ int sa[256], sb[256];
    const int b = blockIdx.x, t = threadIdx.x;
    const int v = (t < NCHUNK) ? hist[(size_t)t * NB + b] : 0;
    sa[t] = v;
    __syncthreads();
    int *cur = sa, *nxt = sb;
    for (int off = 1; off < 256; off <<= 1) {
        nxt[t] = cur[t] + ((t >= off) ? cur[t - off] : 0);
        __syncthreads();
        int* tmp = cur; cur = nxt; nxt = tmp;
    }
    if (t < NCHUNK) hist[(size_t)t * NB + b] = cur[t] - v;   // exclusive
    if (t == 255) btotal[b] = cur[255];
}

// ---- build pass 3: single-block chunked exclusive scan of bucket totals ----
__global__ __launch_bounds__(1024) void base_scan(
    const int* __restrict__ btotal, int* __restrict__ bstart, int NB, int E) {
    __shared__ int sa[1024], sb[1024];
    __shared__ int carry;
    const int t = threadIdx.x;
    if (t == 0) carry = 0;
    __syncthreads();
    for (int base = 0; base < NB; base += 1024) {
        const int i = base + t;
        const int v = (i < NB) ? btotal[i] : 0;
        sa[t] = v;
        __syncthreads();
        int *cur = sa, *nxt = sb;
        for (int off = 1; off < 1024; off <<= 1) {
            nxt[t] = cur[t] + ((t >= off) ? cur[t - off] : 0);
            __syncthreads();
            int* tmp = cur; cur = nxt; nxt = tmp;
        }
        const int c = carry;
        if (i < NB) bstart[i] = c + cur[t] - v;
        __syncthreads();
        if (t == 1023) carry = c + cur[1023];
        __syncthreads();
    }
    if (t == 0) bstart[NB] = E;
}

// ---- build pass 4: scatter packed (dstlow<<26 | src) via per-block LDS cursors ----
__global__ __launch_bounds__(1024) void scatter_pack(
    const int* __restrict__ src, const int* __restrict__ dst,
    const int* __restrict__ prebase, const int* __restrict__ bstart,
    unsigned int* __restrict__ packed, int E, int NB) {
    __shared__ int cur[MAX_NB];
    const int k = blockIdx.x;
    for (int b = threadIdx.x; b < NB; b += 1024)
        cur[b] = bstart[b] + prebase[(size_t)k * NB + b];
    __syncthreads();
    const int e0 = k * CH, e1 = min(E, e0 + CH);
    for (int e = e0 + threadIdx.x; e < e1; e += 1024) {
        const int d = dst[e];
        const int p = atomicAdd(&cur[d >> 4], 1);
        packed[p] = ((unsigned)(d & 15) << 26) | (unsigned)src[e];
    }
}

// ---- build pass 5: in-place counting sort of each bucket by dst-low ----
__global__ __launch_bounds__(256) void sort_bucket(
    unsigned int* packed, const int* __restrict__ bstart, int NB) {
    __shared__ unsigned ent[SORT_CAP];
    __shared__ int cnt[16];
    const int b = blockIdx.x;
    const int beg = bstart[b], end = bstart[b + 1];
    const int n = end - beg;
    if (n > SORT_CAP) return;           // uniform per block: safe
    const int t = threadIdx.x;
    if (t < 16) cnt[t] = 0;
    __syncthreads();
    for (int i = t; i < n; i += 256) {
        const unsigned v = packed[beg + i];
        ent[i] = v;
        atomicAdd(&cnt[v >> 26], 1);
    }
    __syncthreads();
    if (t == 0) {
        int run = 0;
        for (int i = 0; i < 16; ++i) { const int c = cnt[i]; cnt[i] = run; run += c; }
    }
    __syncthreads();
    for (int i = t; i < n; i += 256) {
        const unsigned v = ent[i];
        const int p = atomicAdd(&cnt[v >> 26], 1);
        packed[beg + p] = v;
    }
}

// ---- fused aggregate + project: FOUR waves per bucket, readlane edge stream ----
// hs bf16, accumulation fp32. mode=1: out bf16 (next-layer hs); mode=0: fp32 final.
__global__ __launch_bounds__(256) void agg_proj(
    const unsigned int* __restrict__ packed, const int* __restrict__ bstart,
    const unsigned short* __restrict__ hs, const float* __restrict__ norm,
    const float* __restrict__ W, const float* __restrict__ bias,
    void* __restrict__ outv, int N, int mode) {
    __shared__ float acc[4][TILE * FEATS];     // 4 stripes x 4 KB, wave-private
    const int lane = threadIdx.x & 63;
    const int w    = threadIdx.x >> 6;
    const int b    = blockIdx.x;               // one bucket per block
    float* A = acc[w];
#pragma unroll
    for (int i = 0; i < TILE; ++i) A[i * FEATS + lane] = 0.f;

    const int beg = bstart[b], end = bstart[b + 1];
    const int n   = end - beg;
    const int q0  = beg + ((n * w) >> 2);      // this wave's quarter
    const int q1  = beg + ((n * (w + 1)) >> 2);

    int   cur  = -1;                           // current dst-low run (scalar)
    float racc = 0.f;                          // run accumulator (per-lane)
    int   va[16], vb[16];                      // uniform -> SGPRs
    float xa[16], xb[16];

    auto loadPK = [&](int base) -> unsigned {  // 64 edge words in ONE wave load
        int idx = base + lane;
        if (idx > end - 1) idx = end - 1;      // clamp: stays inside this bucket
        return packed[idx];
    };
    auto XTR = [&](unsigned pk, int sub, int* vv) {
#pragma unroll
        for (int j = 0; j < 16; ++j)
            vv[j] = __builtin_amdgcn_readlane((int)pk, sub * 16 + j);
    };
    auto LOADX = [&](const int* vv, float* xx) {
#pragma unroll
        for (int j = 0; j < 16; ++j)
            xx[j] = bf2f(hs[(size_t)((unsigned)vv[j] & 0x3FFFFFFu) * FEATS + lane]);
    };
    auto CONSUME = [&](const int* vv, const float* xx) {
#pragma unroll
        for (int j = 0; j < 16; ++j) {
            const int dl = (int)((unsigned)vv[j] >> 26);
            if (dl != cur) {                   // wave-uniform branch
                if (cur >= 0) A[cur * FEATS + lane] += racc;
                racc = 0.f; cur = dl;
            }
            racc += xx[j];
        }
    };

    const int nq = q1 - q0;
    const int nfull = nq >> 4;
    if (nfull > 0) {
        unsigned pk_cur = loadPK(q0);          // macro-batch 0 (sub 0..3)
        unsigned pk_nxt = loadPK(q0 + 64);     // macro-batch 1, one ahead
        XTR(pk_cur, 0, va); LOADX(va, xa);
        for (int k = 1; k < nfull; ++k) {
            const int sub = k & 3;
            if (sub == 0) { pk_cur = pk_nxt; pk_nxt = loadPK(q0 + k * 16 + 64); }
            // issue X(k) BEFORE consuming k-1: latency hidden under consume
            if (k & 1) { XTR(pk_cur, sub, vb); LOADX(vb, xb); CONSUME(va, xa); }
            else       { XTR(pk_cur, sub, va); LOADX(va, xa); CONSUME(vb, xb); }
        }
        if (nfull & 1) CONSUME(va, xa); else CONSUME(vb, xb);
    }
    for (int e = q0 + nfull * 16; e < q1; ++e) {   // scalar tail
        const unsigned v = (unsigned)__builtin_amdgcn_readfirstlane((int)packed[e]);
        const int dl = (int)(v >> 26);
        const float x = bf2f(hs[(size_t)(v & 0x3FFFFFFu) * FEATS + lane]);
        if (dl != cur) { if (cur >= 0) A[cur * FEATS + lane] += racc; racc = 0.f; cur = dl; }
        racc += x;
    }
    if (cur >= 0) A[cur * FEATS + lane] += racc;   // final flush

    __syncthreads();

    // merge 4 stripes for the rows this wave projects (rows w*4 .. w*4+3);
    // each wave merges exactly what it then reads -- no second barrier.
    {
        const int t4 = w * 64 + lane;          // float4 index into a stripe
        float4 m        = reinterpret_cast<float4*>(acc[0])[t4];
        const float4 x1 = reinterpret_cast<float4*>(acc[1])[t4];
        const float4 x2 = reinterpret_cast<float4*>(acc[2])[t4];
        const float4 x3 = reinterpret_cast<float4*>(acc[3])[t4];
        m.x += x1.x + x2.x + x3.x;
        m.y += x1.y + x2.y + x3.y;
        m.z += x1.z + x2.z + x3.z;
        m.w += x1.w + x2.w + x3.w;
        reinterpret_cast<float4*>(acc[0])[t4] = m;
    }

    float wc[FEATS];
#pragma unroll
    for (int k = 0; k < FEATS; ++k) wc[k] = W[k * FEATS + lane];
    const float bi = bias[lane];

    const int node0 = b * TILE + w * 4;
#pragma unroll
    for (int i = 0; i < 4; ++i) {
        const int node = node0 + i;
        if (node >= N) break;
        const float4* Ar = reinterpret_cast<const float4*>(&acc[0][(w * 4 + i) * FEATS]);
        float s = 0.f;
#pragma unroll
        for (int k4 = 0; k4 < 16; ++k4) {
            const float4 a = Ar[k4];           // wave-uniform ds_read_b128
            s = fmaf(a.x, wc[4 * k4 + 0], s);
            s = fmaf(a.y, wc[4 * k4 + 1], s);
            s = fmaf(a.z, wc[4 * k4 + 2], s);
            s = fmaf(a.w, wc[4 * k4 + 3], s);
        }
        const float nv = norm[node];
        float o = fmaf(s, nv, bi);
        if (mode) {                            // relu + next prescale -> bf16 hs
            o = fmaxf(o, 0.f) * nv;
            ((unsigned short*)outv)[(size_t)node * FEATS + lane] = f2bf(o);
        } else {                               // final fp32
            ((float*)outv)[(size_t)node * FEATS + lane] = o;
        }
    }
}

extern "C" void kernel_launch(void* const* d_in, const int* in_sizes, int n_in,
                              void* d_out, int out_size, void* d_ws, size_t ws_size,
                              hipStream_t stream) {
    const float* feat = (const float*)d_in[0];
    const float* norm = (const float*)d_in[1];
    const int*   src  = (const int*)d_in[2];
    const int*   dst  = (const int*)d_in[3];
    const float* W0   = (const float*)d_in[4];
    const float* b0   = (const float*)d_in[5];
    const float* W1   = (const float*)d_in[6];
    const float* b1   = (const float*)d_in[7];
    const float* W2   = (const float*)d_in[8];
    const float* b2   = (const float*)d_in[9];

    float* out = (float*)d_out;
    const int N = in_sizes[0] / FEATS;
    const int E = in_sizes[2];
    const int NB = (N + TILE - 1) / TILE;          // 6250
    const int NCHUNK = (E + CH - 1) / CH;          // 196

    // workspace layout (~31 MB)
    unsigned short* H0 = (unsigned short*)d_ws;            // [N*64] bf16 ping
    unsigned short* H1 = H0 + (size_t)N * FEATS;           // [N*64] bf16 pong
    unsigned* packed = (unsigned*)(H1 + (size_t)N * FEATS);// [E]
    int*      hist   = (int*)(packed + E);                 // [NCHUNK*NB]
    int*      btotal = hist + (size_t)NCHUNK * NB;         // [NB]
    int*      bstart = btotal + NB;                        // [NB+1]

    // ---- build sorted-bucket edge list (once, reused by 3 layers) ----
    hist_pass<<<NCHUNK, 1024, 0, stream>>>(dst, hist, E, NB);
    bucket_scan<<<NB, 256, 0, stream>>>(hist, btotal, NB, NCHUNK);
    base_scan<<<1, 1024, 0, stream>>>(btotal, bstart, NB, E);
    scatter_pack<<<NCHUNK, 1024, 0, stream>>>(src, dst, hist, bstart, packed, E, NB);
    sort_bucket<<<NB, 256, 0, stream>>>(packed, bstart, NB);

    const int sgrid = (N * 16 + 255) / 256;        // N*64/4 quads

    // hs0 = bf16(feat*norm)
    scale_kernel<<<sgrid, 256, 0, stream>>>(feat, norm, H0, N * 16);

    // layer 0: H0 -> H1 (bf16 hs1)
    agg_proj<<<NB, 256, 0, stream>>>(packed, bstart, H0, norm, W0, b0, H1, N, 1);
    // layer 1: H1 -> H0 (bf16 hs2)
    agg_proj<<<NB, 256, 0, stream>>>(packed, bstart, H1, norm, W1, b1, H0, N, 1);
    // layer 2: H0 -> out (fp32 final)
    agg_proj<<<NB, 256, 0, stream>>>(packed, bstart, H0, norm, W2, b2, out, N, 0);
}

// Round 9
// 219.883 us; speedup vs baseline: 1.4336x; 1.4336x over previous
//
#include <hip/hip_runtime.h>

#define FEATS 64
#define BTILE 32         // dst nodes per build bucket (dl field: 6 bits avail, 5 used)
#define MAX_NB 3200      // supports N <= 102400 at BTILE=32
#define CH 8192          // edges per build chunk (196 chunks)
#define SORT_CAP 2048    // max bucket size sorter handles (avg 512, sigma 23)
#define NPW 8            // nodes per wave in agg_proj

__device__ __forceinline__ float bf2f(unsigned short b) {
    unsigned u = (unsigned)b << 16;
    float f; __builtin_memcpy(&f, &u, 4); return f;
}
__device__ __forceinline__ unsigned short f2bf(float f) {   // round-to-nearest-even
    unsigned u; __builtin_memcpy(&u, &f, 4);
    u += 0x7FFFu + ((u >> 16) & 1u);
    return (unsigned short)(u >> 16);
}
__device__ __forceinline__ float lo16(unsigned u) {
    unsigned v = u << 16; float f; __builtin_memcpy(&f, &v, 4); return f;
}
__device__ __forceinline__ float hi16(unsigned u) {
    unsigned v = u & 0xFFFF0000u; float f; __builtin_memcpy(&f, &v, 4); return f;
}

// ---- scale: hs = bf16(feat * norm); 4 elems/thread ----
__global__ __launch_bounds__(256) void scale_kernel(
    const float* __restrict__ feat, const float* __restrict__ norm,
    unsigned short* __restrict__ out, int n4) {
    const int i = blockIdx.x * 256 + threadIdx.x;
    if (i >= n4) return;
    float4 v = reinterpret_cast<const float4*>(feat)[i];
    const float nv = norm[i >> 4];
    uint2 p;
    p.x = (unsigned)f2bf(v.x * nv) | ((unsigned)f2bf(v.y * nv) << 16);
    p.y = (unsigned)f2bf(v.z * nv) | ((unsigned)f2bf(v.w * nv) << 16);
    reinterpret_cast<uint2*>(out)[i] = p;
}

// ---- build pass 1: per-chunk histogram over dst buckets ----
__global__ __launch_bounds__(1024) void hist_pass(
    const int* __restrict__ dst, int* __restrict__ hist, int E, int NB) {
    __shared__ int lh[MAX_NB];
    for (int i = threadIdx.x; i < NB; i += 1024) lh[i] = 0;
    __syncthreads();
    const int k  = blockIdx.x;
    const int e0 = k * CH, e1 = min(E, e0 + CH);
    for (int e = e0 + threadIdx.x; e < e1; e += 1024)
        atomicAdd(&lh[dst[e] >> 5], 1);
    __syncthreads();
    for (int b = threadIdx.x; b < NB; b += 1024)
        hist[(size_t)k * NB + b] = lh[b];
}

// ---- build pass 2: per-bucket exclusive scan across chunks (in place), totals ----
__global__ __launch_bounds__(256) void bucket_scan(
    int* hist, int* __restrict__ btotal, int NB, int NCHUNK) {
    __shared__ int sa[256], sb[256];
    const int b = blockIdx.x, t = threadIdx.x;
    const int v = (t < NCHUNK) ? hist[(size_t)t * NB + b] : 0;
    sa[t] = v;
    __syncthreads();
    int *cur = sa, *nxt = sb;
    for (int off = 1; off < 256; off <<= 1) {
        nxt[t] = cur[t] + ((t >= off) ? cur[t - off] : 0);
        __syncthreads();
        int* tmp = cur; cur = nxt; nxt = tmp;
    }
    if (t < NCHUNK) hist[(size_t)t * NB + b] = cur[t] - v;   // exclusive
    if (t == 255) btotal[b] = cur[255];
}

// ---- build pass 3: single-block chunked exclusive scan of bucket totals ----
__global__ __launch_bounds__(1024) void base_scan(
    const int* __restrict__ btotal, int* __restrict__ bstart, int NB, int E) {
    __shared__ int sa[1024], sb[1024];
    __shared__ int carry;
    const int t = threadIdx.x;
    if (t == 0) carry = 0;
    __syncthreads();
    for (int base = 0; base < NB; base += 1024) {
        const int i = base + t;
        const int v = (i < NB) ? btotal[i] : 0;
        sa[t] = v;
        __syncthreads();
        int *cur = sa, *nxt = sb;
        for (int off = 1; off < 1024; off <<= 1) {
            nxt[t] = cur[t] + ((t >= off) ? cur[t - off] : 0);
            __syncthreads();
            int* tmp = cur; cur = nxt; nxt = tmp;
        }
        const int c = carry;
        if (i < NB) bstart[i] = c + cur[t] - v;
        __syncthreads();
        if (t == 1023) carry = c + cur[1023];
        __syncthreads();
    }
    if (t == 0) bstart[NB] = E;
}

// ---- build pass 4: scatter packed (dstlow<<26 | src) via per-block LDS cursors ----
__global__ __launch_bounds__(1024) void scatter_pack(
    const int* __restrict__ src, const int* __restrict__ dst,
    const int* __restrict__ prebase, const int* __restrict__ bstart,
    unsigned int* __restrict__ packed, int E, int NB) {
    __shared__ int cur[MAX_NB];
    const int k = blockIdx.x;
    for (int b = threadIdx.x; b < NB; b += 1024)
        cur[b] = bstart[b] + prebase[(size_t)k * NB + b];
    __syncthreads();
    const int e0 = k * CH, e1 = min(E, e0 + CH);
    for (int e = e0 + threadIdx.x; e < e1; e += 1024) {
        const int d = dst[e];
        const int p = atomicAdd(&cur[d >> 5], 1);
        packed[p] = ((unsigned)(d & 31) << 26) | (unsigned)src[e];
    }
}

// ---- build pass 5: in-place counting sort of each bucket by dst-low + node rowptr ----
__global__ __launch_bounds__(256) void sort_bucket(
    unsigned int* packed, const int* __restrict__ bstart,
    int* __restrict__ rowptr, int NB, int E) {
    __shared__ unsigned ent[SORT_CAP];
    __shared__ int cnt[BTILE];
    __shared__ int base[BTILE];
    const int b = blockIdx.x;
    const int beg = bstart[b], end = bstart[b + 1];
    const int n = end - beg;
    const int t = threadIdx.x;
    if (t < BTILE) cnt[t] = 0;
    __syncthreads();
    if (n <= SORT_CAP) {
        for (int i = t; i < n; i += 256) {
            const unsigned v = packed[beg + i];
            ent[i] = v;
            atomicAdd(&cnt[v >> 26], 1);
        }
    } else {
        for (int i = t; i < n; i += 256) atomicAdd(&cnt[packed[beg + i] >> 26], 1);
    }
    __syncthreads();
    if (t == 0) {                        // exclusive scan -> run starts
        int run = 0;
        for (int i = 0; i < BTILE; ++i) {
            const int c = cnt[i]; base[i] = run; cnt[i] = run; run += c;
        }
    }
    __syncthreads();
    if (t < BTILE) rowptr[b * BTILE + t] = beg + base[t];   // node-level rowptr
    if (b == NB - 1 && t == 0) rowptr[NB * BTILE] = E;
    if (n <= SORT_CAP) {
        for (int i = t; i < n; i += 256) {
            const unsigned v = ent[i];
            const int p = atomicAdd(&cnt[v >> 26], 1);
            packed[beg + p] = v;
        }
    }
}

#define ACC8(d, m) do { \
    a0 = fmaf(lo16((d).x), (m), a0); a1 = fmaf(hi16((d).x), (m), a1); \
    a2 = fmaf(lo16((d).y), (m), a2); a3 = fmaf(hi16((d).y), (m), a3); \
    a4 = fmaf(lo16((d).z), (m), a4); a5 = fmaf(hi16((d).z), (m), a5); \
    a6 = fmaf(lo16((d).w), (m), a6); a7 = fmaf(hi16((d).w), (m), a7); } while (0)

#define RED(off) do { \
    a0 += __shfl_xor(a0, off, 64); a1 += __shfl_xor(a1, off, 64); \
    a2 += __shfl_xor(a2, off, 64); a3 += __shfl_xor(a3, off, 64); \
    a4 += __shfl_xor(a4, off, 64); a5 += __shfl_xor(a5, off, 64); \
    a6 += __shfl_xor(a6, off, 64); a7 += __shfl_xor(a7, off, 64); } while (0)

__device__ __forceinline__ uint4 row16(const unsigned short* hs, unsigned pk, int chunk) {
    return *((const uint4*)((const char*)hs + (size_t)(pk & 0x3FFFFFFu) * 128) + chunk);
}

// ---- fused aggregate + project: ONE WAVE per block, 8 nodes, octet gather ----
// Octet = 8 edges per VMEM instr: lane (slot=lane>>3, chunk=lane&7) loads 16B of
// row src[slot]. Register accumulate + butterfly reduce; write-once LDS rows.
__global__ __launch_bounds__(64, 4) void agg_proj(
    const unsigned int* __restrict__ packed, const int* __restrict__ rowptr,
    const unsigned short* __restrict__ hs, const float* __restrict__ norm,
    const float* __restrict__ W, const float* __restrict__ bias,
    void* __restrict__ outv, int N, int E, int mode) {
    __shared__ float accs[NPW * FEATS];          // 2 KB, wave-private
    const int lane  = threadIdx.x & 63;
    const int slot  = lane >> 3;
    const int chunk = lane & 7;
    const int node0 = blockIdx.x * NPW;

    // hoist first-segment edge words for all 8 nodes (8 independent loads in flight)
    int rbv[NPW], rev[NPW];
    unsigned c[NPW];
#pragma unroll
    for (int i = 0; i < NPW; ++i) {
        const int node = node0 + i;
        const int cl = node < N ? node : N - 1;
        rbv[i] = rowptr[cl];
        rev[i] = (node < N) ? rowptr[cl + 1] : rbv[i];
        c[i]   = packed[min(rbv[i] + lane, E - 1)];
    }

#pragma unroll
    for (int i = 0; i < NPW; ++i) {
        float a0 = 0.f, a1 = 0.f, a2 = 0.f, a3 = 0.f,
              a4 = 0.f, a5 = 0.f, a6 = 0.f, a7 = 0.f;
        const int deg = rev[i] - rbv[i];
        if (deg > 0) {
            const int segn = min(deg, 64);
            const int no   = (segn + 7) >> 3;
            unsigned pk = (unsigned)__builtin_amdgcn_ds_bpermute(slot << 2, (int)c[i]);
            uint4 d = row16(hs, pk, chunk);
            float m = (slot < segn) ? 1.f : 0.f;
            for (int o = 1; o < no; ++o) {         // 2-deep: next loads before consume
                const int idx = o * 8 + slot;
                unsigned pk1 = (unsigned)__builtin_amdgcn_ds_bpermute(idx << 2, (int)c[i]);
                uint4 d1 = row16(hs, pk1, chunk);
                ACC8(d, m);
                d = d1; m = (idx < segn) ? 1.f : 0.f;
            }
            ACC8(d, m);
            for (int p = rbv[i] + 64; p < rev[i]; p += 64) {   // rare: deg > 64
                const int sn = min(rev[i] - p, 64);
                const unsigned cw2 = packed[min(p + lane, E - 1)];
                const int no2 = (sn + 7) >> 3;
                for (int o = 0; o < no2; ++o) {
                    const int idx = o * 8 + slot;
                    unsigned pk2 = (unsigned)__builtin_amdgcn_ds_bpermute(idx << 2, (int)cw2);
                    uint4 d2 = row16(hs, pk2, chunk);
                    const float m2 = (idx < sn) ? 1.f : 0.f;
                    ACC8(d2, m2);
                }
            }
        }
        RED(8); RED(16); RED(32);                  // reduce over slot bits
        if (slot == 0) {                           // write-once row (no RMW)
            float4* dst = (float4*)&accs[i * FEATS + chunk * 8];
            dst[0] = make_float4(a0, a1, a2, a3);
            dst[1] = make_float4(a4, a5, a6, a7);
        }
    }
    __syncthreads();                               // single wave: trivial

    // epilogue: project 8 rows; lane = output feature; W column in regs
    float wc[FEATS];
#pragma unroll
    for (int k = 0; k < FEATS; ++k) wc[k] = W[k * FEATS + lane];
    const float bi = bias[lane];
#pragma unroll
    for (int i = 0; i < NPW; ++i) {
        const int node = node0 + i;
        if (node >= N) break;
        const float4* Ar = (const float4*)&accs[i * FEATS];
        float s = 0.f;
#pragma unroll
        for (int k4 = 0; k4 < 16; ++k4) {
            const float4 a = Ar[k4];               // wave-uniform ds_read_b128
            s = fmaf(a.x, wc[4 * k4 + 0], s);
            s = fmaf(a.y, wc[4 * k4 + 1], s);
            s = fmaf(a.z, wc[4 * k4 + 2], s);
            s = fmaf(a.w, wc[4 * k4 + 3], s);
        }
        const float nv = norm[node];
        float o = fmaf(s, nv, bi);
        if (mode) {                                // relu + next prescale -> bf16
            o = fmaxf(o, 0.f) * nv;
            ((unsigned short*)outv)[(size_t)node * FEATS + lane] = f2bf(o);
        } else {                                   // final fp32
            ((float*)outv)[(size_t)node * FEATS + lane] = o;
        }
    }
}

extern "C" void kernel_launch(void* const* d_in, const int* in_sizes, int n_in,
                              void* d_out, int out_size, void* d_ws, size_t ws_size,
                              hipStream_t stream) {
    const float* feat = (const float*)d_in[0];
    const float* norm = (const float*)d_in[1];
    const int*   src  = (const int*)d_in[2];
    const int*   dst  = (const int*)d_in[3];
    const float* W0   = (const float*)d_in[4];
    const float* b0   = (const float*)d_in[5];
    const float* W1   = (const float*)d_in[6];
    const float* b1   = (const float*)d_in[7];
    const float* W2   = (const float*)d_in[8];
    const float* b2   = (const float*)d_in[9];

    float* out = (float*)d_out;
    const int N = in_sizes[0] / FEATS;
    const int E = in_sizes[2];
    const int NB = (N + BTILE - 1) / BTILE;        // 3125
    const int NCHUNK = (E + CH - 1) / CH;          // 196

    // workspace layout (~35 MB)
    unsigned short* H0 = (unsigned short*)d_ws;             // [N*64] bf16 ping
    unsigned short* H1 = H0 + (size_t)N * FEATS;            // [N*64] bf16 pong
    unsigned* packed = (unsigned*)(H1 + (size_t)N * FEATS); // [E]
    int*      hist   = (int*)(packed + E);                  // [NCHUNK*NB]
    int*      btotal = hist + (size_t)NCHUNK * NB;          // [NB]
    int*      bstart = btotal + NB;                         // [NB+1]
    int*      rowptr = bstart + NB + 1;                     // [NB*BTILE+1]

    // ---- build node-sorted edge list + node rowptr (once, reused by 3 layers) ----
    hist_pass<<<NCHUNK, 1024, 0, stream>>>(dst, hist, E, NB);
    bucket_scan<<<NB, 256, 0, stream>>>(hist, btotal, NB, NCHUNK);
    base_scan<<<1, 1024, 0, stream>>>(btotal, bstart, NB, E);
    scatter_pack<<<NCHUNK, 1024, 0, stream>>>(src, dst, hist, bstart, packed, E, NB);
    sort_bucket<<<NB, 256, 0, stream>>>(packed, bstart, rowptr, NB, E);

    const int agrid = (N + NPW - 1) / NPW;         // 12500 one-wave blocks
    const int sgrid = (N * 16 + 255) / 256;

    // hs0 = bf16(feat*norm)
    scale_kernel<<<sgrid, 256, 0, stream>>>(feat, norm, H0, N * 16);

    // layer 0: H0 -> H1 (bf16 hs1)
    agg_proj<<<agrid, 64, 0, stream>>>(packed, rowptr, H0, norm, W0, b0, H1, N, E, 1);
    // layer 1: H1 -> H0 (bf16 hs2)
    agg_proj<<<agrid, 64, 0, stream>>>(packed, rowptr, H1, norm, W1, b1, H0, N, E, 1);
    // layer 2: H0 -> out (fp32 final)
    agg_proj<<<agrid, 64, 0, stream>>>(packed, rowptr, H0, norm, W2, b2, out, N, E, 0);
}